// Round 15
// baseline (348.877 us; speedup 1.0000x reference)
//
#include <hip/hip_runtime.h>
#include <hip/hip_bf16.h>

typedef __hip_bfloat16 bf16_t;
typedef __attribute__((ext_vector_type(8))) __bf16 bf16x8;
typedef __attribute__((ext_vector_type(4))) float f32x4;
typedef __attribute__((ext_vector_type(8))) unsigned short u16x8;

// ---------------------------------------------------------------- helpers

__device__ __forceinline__ void gld_lds16(const void* g, void* l) {
    // async global->LDS, 16B per lane. LDS dest is wave-uniform base + lane*16.
    __builtin_amdgcn_global_load_lds(
        (const __attribute__((address_space(1))) unsigned int*)g,
        (__attribute__((address_space(3))) unsigned int*)l,
        16, 0, 0);
}

__device__ __forceinline__ unsigned short bf16_bits(float x) {
    bf16_t b = __float2bfloat16(x);
    return *reinterpret_cast<unsigned short*>(&b);
}

// ---------------------------------------------------------------- convert x -> bf16

__global__ __launch_bounds__(256) void cvt_f32_bf16_kernel(
    const float* __restrict__ in, bf16_t* __restrict__ out, long n4) {
    long stride = (long)gridDim.x * blockDim.x;
    for (long i = (long)blockIdx.x * blockDim.x + threadIdx.x; i < n4; i += stride) {
        float4 v = reinterpret_cast<const float4*>(in)[i];
        ushort4 o;
        o.x = bf16_bits(v.x);
        o.y = bf16_bits(v.y);
        o.z = bf16_bits(v.z);
        o.w = bf16_bits(v.w);
        reinterpret_cast<ushort4*>(out)[i] = o;
    }
}

// ---------------------------------------------------------------- transposes

__global__ __launch_bounds__(256) void transpose_f32_bf16_kernel(
    const float* __restrict__ in, bf16_t* __restrict__ out, long ldin, long ldout) {
    __shared__ float tile[32][33];
    int c0 = blockIdx.x * 32, r0 = blockIdx.y * 32;
    int x = threadIdx.x;
#pragma unroll
    for (int yy = 0; yy < 4; ++yy) {
        int y = threadIdx.y + yy * 8;
        tile[y][x] = in[(long)(r0 + y) * ldin + c0 + x];
    }
    __syncthreads();
#pragma unroll
    for (int yy = 0; yy < 4; ++yy) {
        int y = threadIdx.y + yy * 8;
        out[(long)(c0 + y) * ldout + r0 + x] = __float2bfloat16(tile[x][y]);
    }
}

__global__ __launch_bounds__(256) void transpose_bf16_kernel(
    const bf16_t* __restrict__ in, bf16_t* __restrict__ out,
    long ldin, long ldout, long sIn, long sOut) {
    __shared__ bf16_t tile[32][33];
    in  += (long)blockIdx.z * sIn;
    out += (long)blockIdx.z * sOut;
    int c0 = blockIdx.x * 32, r0 = blockIdx.y * 32;
    int x = threadIdx.x;
#pragma unroll
    for (int yy = 0; yy < 4; ++yy) {
        int y = threadIdx.y + yy * 8;
        tile[y][x] = in[(long)(r0 + y) * ldin + c0 + x];
    }
    __syncthreads();
#pragma unroll
    for (int yy = 0; yy < 4; ++yy) {
        int y = threadIdx.y + yy * 8;
        out[(long)(c0 + y) * ldout + r0 + x] = tile[x][y];
    }
}

// ---------------------------------------------------------------- 256x256 8-wave GEMM, 1 barrier / K-tile
// (round-7/10 inner loop - best measured. Schedule variants r5/r6/r8/r11/r12
// all regressed; do not re-derive without new counter evidence.)
// swz_mode=1: panel-resident XCD mapping (qkv FETCH 202MB -> 74MB measured).
// V-fusion: cols >= vsplit -> transposed write to Vt[b][c][t] only.

__global__ __launch_bounds__(512, 2) void gemm256_kernel(
    const bf16_t* __restrict__ A, const bf16_t* __restrict__ Bt,
    void* __restrict__ Cp, const float* __restrict__ bias,
    float scale, int K,
    long lda, long ldb, long ldc,
    long strideA, long strideB, long strideC,
    int mtiles, int causal_skip, int causal_klimit, int c_f32, int swz_mode,
    bf16_t* __restrict__ Vt, int vsplit)
{
    __shared__ __align__(16) bf16_t As[3][256 * 32];
    __shared__ __align__(16) bf16_t Bs[3][256 * 32];

    int nwg = gridDim.x;
    int bid = blockIdx.x;
    int bm_t, bn_t;
    if (swz_mode == 1 && (mtiles & 7) == 0 && (nwg & 7) == 0) {
        int xcd = bid & 7;
        int l   = bid >> 3;
        int mpx = mtiles >> 3;
        bm_t = xcd * mpx + (l % mpx);   // bm fast: A group L2-resident
        bn_t = l / mpx;                 // bn slow: B-panels stream
    } else {
        int swz = (bid & 7) * (nwg >> 3) + (bid >> 3);
        bm_t = swz % mtiles; bn_t = swz / mtiles;
    }
    if (causal_skip && bn_t > bm_t) return;
    long bm0 = (long)bm_t * 256, bn0 = (long)bn_t * 256;

    int b = blockIdx.z;
    const char* Ab = (const char*)(A + (long)b * strideA + bm0 * lda);
    const char* Bb = (const char*)(Bt + (long)b * strideB + bn0 * ldb);
    long ldab = lda * 2, ldbb = ldb * 2;

    int tid = threadIdx.x, wave = tid >> 6, lane = tid & 63;
    int wm = wave >> 2, wn = wave & 3;
    int lr = lane & 15, kc = lane >> 4;

    int Kend = K;
    if (causal_klimit) { long kl = bm0 + 256; Kend = (kl < (long)K) ? (int)kl : K; }
    int NT = Kend >> 5;

    int offw = wave * 1024 + lane * 16;
    int rih  = offw >> 6;
    long colswz = (long)(((lane & 3) ^ ((rih >> 1) & 3)) << 4);
    long rowbA0 = (long)rih * ldab, rowbA1 = (long)(rih + 128) * ldab;
    long rowbB0 = (long)rih * ldbb, rowbB1 = (long)(rih + 128) * ldbb;
    int ldsoff = wave * 1024;

    auto STA = [&](int t, int h, int buf) {
        gld_lds16(Ab + (h ? rowbA1 : rowbA0) + (long)t * 64 + colswz,
                  (char*)As + buf * 16384 + h * 8192 + ldsoff);
    };
    auto STB = [&](int t, int h, int buf) {
        gld_lds16(Bb + (h ? rowbB1 : rowbB0) + (long)t * 64 + colswz,
                  (char*)Bs + buf * 16384 + h * 8192 + ldsoff);
    };

    int aoff[8], boff[4];
#pragma unroll
    for (int m = 0; m < 8; ++m) {
        int row = wm * 128 + m * 16 + lr;
        aoff[m] = (row * 64 + kc * 16) ^ (((row >> 1) & 3) << 4);
    }
#pragma unroll
    for (int n = 0; n < 4; ++n) {
        int row = wn * 64 + n * 16 + lr;
        boff[n] = (row * 64 + kc * 16) ^ (((row >> 1) & 3) << 4);
    }

    f32x4 acc[8][4];
#pragma unroll
    for (int m = 0; m < 8; ++m)
#pragma unroll
        for (int n = 0; n < 4; ++n) acc[m][n] = (f32x4){0.f, 0.f, 0.f, 0.f};

    STA(0, 0, 0); STA(0, 1, 0); STB(0, 0, 0); STB(0, 1, 0);
    STA(1, 0, 1); STA(1, 1, 1); STB(1, 0, 1); STB(1, 1, 1);
    asm volatile("s_waitcnt vmcnt(4)" ::: "memory");
    __builtin_amdgcn_s_barrier();

    int cur = 0;

    for (int t = 0; t < NT; ++t) {
        int b2 = cur + 2; if (b2 >= 3) b2 -= 3;
        int t2 = (t + 2 < NT) ? (t + 2) : NT - 1;
        const char* Ac = (const char*)As + cur * 16384;
        const char* Bc = (const char*)Bs + cur * 16384;

        bf16x8 alo[4], ahi[4], bfr[4];
#pragma unroll
        for (int m = 0; m < 4; ++m) alo[m] = *(const bf16x8*)(Ac + aoff[m]);
#pragma unroll
        for (int n = 0; n < 4; ++n) bfr[n] = *(const bf16x8*)(Bc + boff[n]);
#pragma unroll
        for (int m = 0; m < 4; ++m) ahi[m] = *(const bf16x8*)(Ac + aoff[m + 4]);

        STA(t2, 0, b2); STA(t2, 1, b2);
        STB(t2, 0, b2); STB(t2, 1, b2);
        __builtin_amdgcn_sched_barrier(0);

        __builtin_amdgcn_s_setprio(1);
#pragma unroll
        for (int m = 0; m < 4; ++m)
#pragma unroll
            for (int n = 0; n < 4; ++n)
                acc[m][n] = __builtin_amdgcn_mfma_f32_16x16x32_bf16(alo[m], bfr[n], acc[m][n], 0, 0, 0);
#pragma unroll
        for (int m = 0; m < 4; ++m)
#pragma unroll
            for (int n = 0; n < 4; ++n)
                acc[m + 4][n] = __builtin_amdgcn_mfma_f32_16x16x32_bf16(ahi[m], bfr[n], acc[m + 4][n], 0, 0, 0);
        __builtin_amdgcn_s_setprio(0);

        asm volatile("s_waitcnt vmcnt(4)" ::: "memory");
        __builtin_amdgcn_s_barrier();

        cur += 1; if (cur >= 3) cur -= 3;
    }

    asm volatile("s_waitcnt vmcnt(0)" ::: "memory");

#pragma unroll
    for (int m = 0; m < 8; ++m) {
        long row = bm0 + wm * 128 + m * 16 + kc * 4;
#pragma unroll
        for (int n = 0; n < 4; ++n) {
            long col = bn0 + wn * 64 + n * 16 + lr;
            float bv = bias ? bias[col] : 0.f;
            if (Vt && col >= vsplit) {
                long bb = row >> 11;            // T = 2048
                long tl = row & 2047;
                ushort4 pk;
                pk.x = bf16_bits(acc[m][n][0] * scale + bv);
                pk.y = bf16_bits(acc[m][n][1] * scale + bv);
                pk.z = bf16_bits(acc[m][n][2] * scale + bv);
                pk.w = bf16_bits(acc[m][n][3] * scale + bv);
                *reinterpret_cast<ushort4*>(
                    Vt + bb * 2097152 + (col - vsplit) * 2048 + tl) = pk;
            } else if (c_f32) {
                float* Crow = (float*)Cp + (long)b * strideC;
#pragma unroll
                for (int r = 0; r < 4; ++r)
                    Crow[(row + r) * ldc + col] = acc[m][n][r] * scale + bv;
            } else {
                bf16_t* Crow = (bf16_t*)Cp + (long)b * strideC;
#pragma unroll
                for (int r = 0; r < 4; ++r)
                    Crow[(row + r) * ldc + col] = __float2bfloat16(acc[m][n][r] * scale + bv);
            }
        }
    }
}

// ---------------------------------------------------------------- 128x256 8-wave GEMM (half-quantum, used for PV)
// Same verified inner-loop pattern as gemm256; M=128, wave tile 64x64,
// acc[4][4] (64 regs) -> __launch_bounds__(512,4) targets 2 blocks/CU.
// LDS: 3 bufs x (A[128][32] 8KB + B[256][32] 16KB) = 72 KiB.
// causal_klimit: Kend = min(bm0+128, K). Safe vs softmax zero-fill: for all
// rows t in the tile, klim(t) = ((t>>8)+1)<<8 >= bm0+128 = Kend, so every
// read S entry is real P or an explicitly stored zero.

__global__ __launch_bounds__(512, 4) void gemm128_kernel(
    const bf16_t* __restrict__ A, const bf16_t* __restrict__ Bt,
    bf16_t* __restrict__ C,
    float scale, int K,
    long lda, long ldb, long ldc,
    long strideA, long strideB, long strideC,
    int mtiles, int causal_skip, int causal_klimit)
{
    __shared__ __align__(16) bf16_t As[3][128 * 32];
    __shared__ __align__(16) bf16_t Bs[3][256 * 32];

    int nwg = gridDim.x;
    int bid = blockIdx.x;
    int swz = ((nwg & 7) == 0) ? (bid & 7) * (nwg >> 3) + (bid >> 3) : bid;
    int bm_t = swz % mtiles, bn_t = swz / mtiles;
    long bm0 = (long)bm_t * 128, bn0 = (long)bn_t * 256;
    if (causal_skip && bn0 > bm0 + 127) return;

    int b = blockIdx.z;
    const char* Ab = (const char*)(A + (long)b * strideA + bm0 * lda);
    const char* Bb = (const char*)(Bt + (long)b * strideB + bn0 * ldb);
    long ldab = lda * 2, ldbb = ldb * 2;

    int tid = threadIdx.x, wave = tid >> 6, lane = tid & 63;
    int wm = wave >> 2, wn = wave & 3;   // wm 0..1, wn 0..3
    int lr = lane & 15, kc = lane >> 4;

    int Kend = K;
    if (causal_klimit) { long kl = bm0 + 128; Kend = (kl < (long)K) ? (int)kl : K; }
    int NT = Kend >> 5;                  // >= 4 for all shapes here

    int offw = wave * 1024 + lane * 16;
    int rih  = offw >> 6;                // row 0..127
    long colswz = (long)(((lane & 3) ^ ((rih >> 1) & 3)) << 4);
    long rowbA = (long)rih * ldab;
    long rowbB0 = (long)rih * ldbb, rowbB1 = (long)(rih + 128) * ldbb;
    int ldsoff = wave * 1024;

    auto STA = [&](int t, int buf) {     // full A tile (128 rows) = 1 call
        gld_lds16(Ab + rowbA + (long)t * 64 + colswz,
                  (char*)As + buf * 8192 + ldsoff);
    };
    auto STB = [&](int t, int h, int buf) {
        gld_lds16(Bb + (h ? rowbB1 : rowbB0) + (long)t * 64 + colswz,
                  (char*)Bs + buf * 16384 + h * 8192 + ldsoff);
    };

    int aoff[4], boff[4];
#pragma unroll
    for (int m = 0; m < 4; ++m) {
        int row = wm * 64 + m * 16 + lr;
        aoff[m] = (row * 64 + kc * 16) ^ (((row >> 1) & 3) << 4);
    }
#pragma unroll
    for (int n = 0; n < 4; ++n) {
        int row = wn * 64 + n * 16 + lr;
        boff[n] = (row * 64 + kc * 16) ^ (((row >> 1) & 3) << 4);
    }

    f32x4 acc[4][4];
#pragma unroll
    for (int m = 0; m < 4; ++m)
#pragma unroll
        for (int n = 0; n < 4; ++n) acc[m][n] = (f32x4){0.f, 0.f, 0.f, 0.f};

    STA(0, 0); STB(0, 0, 0); STB(0, 1, 0);
    STA(1, 1); STB(1, 0, 1); STB(1, 1, 1);
    asm volatile("s_waitcnt vmcnt(3)" ::: "memory");
    __builtin_amdgcn_s_barrier();

    int cur = 0;
    for (int t = 0; t < NT; ++t) {
        int b2 = cur + 2; if (b2 >= 3) b2 -= 3;
        int t2 = (t + 2 < NT) ? (t + 2) : NT - 1;
        const char* Ac = (const char*)As + cur * 8192;
        const char* Bc = (const char*)Bs + cur * 16384;

        bf16x8 af[4], bfr[4];
#pragma unroll
        for (int m = 0; m < 4; ++m) af[m] = *(const bf16x8*)(Ac + aoff[m]);
#pragma unroll
        for (int n = 0; n < 4; ++n) bfr[n] = *(const bf16x8*)(Bc + boff[n]);

        STA(t2, b2); STB(t2, 0, b2); STB(t2, 1, b2);
        __builtin_amdgcn_sched_barrier(0);

        __builtin_amdgcn_s_setprio(1);
#pragma unroll
        for (int m = 0; m < 4; ++m)
#pragma unroll
            for (int n = 0; n < 4; ++n)
                acc[m][n] = __builtin_amdgcn_mfma_f32_16x16x32_bf16(af[m], bfr[n], acc[m][n], 0, 0, 0);
        __builtin_amdgcn_s_setprio(0);

        asm volatile("s_waitcnt vmcnt(3)" ::: "memory");
        __builtin_amdgcn_s_barrier();

        cur += 1; if (cur >= 3) cur -= 3;
    }

    asm volatile("s_waitcnt vmcnt(0)" ::: "memory");

#pragma unroll
    for (int m = 0; m < 4; ++m) {
        long row = bm0 + wm * 64 + m * 16 + kc * 4;
#pragma unroll
        for (int n = 0; n < 4; ++n) {
            long col = bn0 + wn * 64 + n * 16 + lr;
            bf16_t* Crow = C + (long)b * strideC;
#pragma unroll
            for (int r = 0; r < 4; ++r)
                Crow[(row + r) * ldc + col] = __float2bfloat16(acc[m][n][r] * scale);
        }
    }
}

// ---------------------------------------------------------------- causal softmax (in-place, bf16)

__global__ __launch_bounds__(256) void softmax_causal_kernel(bf16_t* S, int T) {
    int t = blockIdx.x;
    bf16_t* row = S + ((long)blockIdx.y * T + t) * (long)T;
    int tid = threadIdx.x;
    int s0 = tid * 8;
    int klim = ((t >> 8) + 1) << 8;

    u16x8 raw = {};
    if (s0 <= t) raw = *reinterpret_cast<const u16x8*>(&row[s0]);
    float v[8];
#pragma unroll
    for (int j = 0; j < 8; ++j) v[j] = __uint_as_float(((unsigned)raw[j]) << 16);

    float m = -1e30f;
#pragma unroll
    for (int j = 0; j < 8; ++j)
        if (s0 + j <= t) m = fmaxf(m, v[j]);

    __shared__ float red[8];
#pragma unroll
    for (int o = 32; o; o >>= 1) m = fmaxf(m, __shfl_xor(m, o, 64));
    if ((tid & 63) == 0) red[tid >> 6] = m;
    __syncthreads();
    m = fmaxf(fmaxf(red[0], red[1]), fmaxf(red[2], red[3]));
    __syncthreads();

    float e[8];
    float sum = 0.f;
#pragma unroll
    for (int j = 0; j < 8; ++j) {
        e[j] = (s0 + j <= t) ? __expf(v[j] - m) : 0.f;
        sum += e[j];
    }
#pragma unroll
    for (int o = 32; o; o >>= 1) sum += __shfl_xor(sum, o, 64);
    if ((tid & 63) == 0) red[tid >> 6] = sum;
    __syncthreads();
    sum = red[0] + red[1] + red[2] + red[3];
    float inv = 1.f / sum;

    if (s0 < klim) {
        u16x8 outp;
#pragma unroll
        for (int j = 0; j < 8; ++j) outp[j] = bf16_bits(e[j] * inv);
        *reinterpret_cast<u16x8*>(&row[s0]) = outp;
    }
}

// ---------------------------------------------------------------- launch

extern "C" void kernel_launch(void* const* d_in, const int* in_sizes, int n_in,
                              void* d_out, int out_size, void* d_ws, size_t ws_size,
                              hipStream_t stream) {
    const int B = 8, T = 2048, C = 1024;
    const int M = B * T;            // 16384
    const int N3 = 3 * C;           // 3072

    const float* x      = (const float*)d_in[0];
    const float* w_attn = (const float*)d_in[1];
    const float* b_attn = (const float*)d_in[2];
    const float* w_proj = (const float*)d_in[3];
    const float* b_proj = (const float*)d_in[4];
    float* out = (float*)d_out;     // reference output dtype is fp32

    char* ws = (char*)d_ws;

    // ---- adaptive workspace tiering ----
    const size_t BASE_FULL = 176160768ull;   // weights + qkv + xbO + vT
    const size_t PER_B     = 8388608ull;     // S per batch
    long NB = 0;
    if (ws_size >= BASE_FULL + PER_B) {
        NB = (long)((ws_size - BASE_FULL) / PER_B);
        if (NB > 8) NB = 8;
    }

    if (NB >= 1) {
        // ---------------- chunked path
        bf16_t* waT = (bf16_t*)(ws);                    // [3C, C]   6.3 MB
        bf16_t* wpT = (bf16_t*)(ws + 6291456);          // [C, C]    2.1 MB
        bf16_t* qkv = (bf16_t*)(ws + 8388608);          // [M, 3C] 100.7 MB (V cols unwritten)
        bf16_t* xbO = (bf16_t*)(ws + 109051904);        // [M, C]   33.5 MB (xb, then O)
        bf16_t* vT  = (bf16_t*)(ws + 142606336);        // [B, C, T] 33.5 MB (fused transposed V)
        bf16_t* S   = (bf16_t*)(ws + 176160768);        // [NB, T, T]

        cvt_f32_bf16_kernel<<<2048, 256, 0, stream>>>(x, xbO, (long)M * C / 4);

        transpose_f32_bf16_kernel<<<dim3(N3 / 32, C / 32, 1), dim3(32, 8), 0, stream>>>(
            w_attn, waT, N3, C);
        transpose_f32_bf16_kernel<<<dim3(C / 32, C / 32, 1), dim3(32, 8), 0, stream>>>(
            w_proj, wpT, C, C);

        // qkv = xb @ w_attn + b_attn  (panel swizzle; V cols -> vT transposed)
        gemm256_kernel<<<dim3((M / 256) * (N3 / 256), 1, 1), 512, 0, stream>>>(
            xbO, waT, qkv, b_attn, 1.0f, C,
            C, C, N3, 0, 0, 0, M / 256, 0, 0, 0, 1, vT, 2 * C);

        for (long b0 = 0; b0 < B; b0 += NB) {
            long nb = (B - b0 < NB) ? (B - b0) : NB;
            const bf16_t* qkv_c = qkv + b0 * (long)T * N3;
            bf16_t* O_c = xbO + b0 * (long)T * C;

            // S = (Q K^T)/sqrt(C), causal block-skip (256-tile, r13 best)
            gemm256_kernel<<<dim3((T / 256) * (T / 256), 1, nb), 512, 0, stream>>>(
                qkv_c, qkv_c + C, S, nullptr, 0.03125f, C,
                N3, N3, T, (long)T * N3, (long)T * N3, (long)T * T, T / 256, 1, 0, 0, 0,
                nullptr, 0);

            softmax_causal_kernel<<<dim3(T, nb), 256, 0, stream>>>(S, T);

            // O = P @ V: 128-row quanta + causal K-limit (fixes 1-block/CU
            // 8x work-spread makespan of the 256 version)
            gemm128_kernel<<<dim3((T / 128) * (C / 256), 1, nb), 512, 0, stream>>>(
                S, vT + b0 * (long)C * T, O_c, 1.0f, T,
                T, T, C, (long)T * T, (long)C * T, (long)T * C, T / 128, 0, 1);
        }

        // out = O @ w_proj + b_proj   (fp32 store, panel swizzle)
        gemm256_kernel<<<dim3((M / 256) * (C / 256), 1, 1), 512, 0, stream>>>(
            xbO, wpT, out, b_proj, 1.0f, C,
            C, C, C, 0, 0, 0, M / 256, 0, 0, 1, 1, nullptr, 0);
    } else {
        // ---------------- per-batch fallback (36 MB total, unfused V)
        bf16_t* waT  = (bf16_t*)(ws);                   // [3C, C]   6.3 MB
        bf16_t* wpT  = (bf16_t*)(ws + 6291456);         // [C, C]    2.1 MB
        bf16_t* xbO  = (bf16_t*)(ws + 8388608);         // [T, C]    4.2 MB
        bf16_t* qkvb = (bf16_t*)(ws + 12582912);        // [T, 3C]  12.6 MB
        bf16_t* vTb  = (bf16_t*)(ws + 25165824);        // [C, T]    4.2 MB
        bf16_t* Sb   = (bf16_t*)(ws + 29360128);        // [T, T]    8.4 MB

        transpose_f32_bf16_kernel<<<dim3(N3 / 32, C / 32, 1), dim3(32, 8), 0, stream>>>(
            w_attn, waT, N3, C);
        transpose_f32_bf16_kernel<<<dim3(C / 32, C / 32, 1), dim3(32, 8), 0, stream>>>(
            w_proj, wpT, C, C);

        for (int b = 0; b < B; ++b) {
            const float* x_b = x + (long)b * T * C;
            float* out_b = out + (long)b * T * C;

            cvt_f32_bf16_kernel<<<1024, 256, 0, stream>>>(x_b, xbO, (long)T * C / 4);

            gemm256_kernel<<<dim3((T / 256) * (N3 / 256), 1, 1), 512, 0, stream>>>(
                xbO, waT, qkvb, b_attn, 1.0f, C,
                C, C, N3, 0, 0, 0, T / 256, 0, 0, 0, 1, nullptr, 0);

            transpose_bf16_kernel<<<dim3(C / 32, T / 32, 1), dim3(32, 8), 0, stream>>>(
                qkvb + 2 * C, vTb, N3, T, 0, 0);

            gemm256_kernel<<<dim3((T / 256) * (T / 256), 1, 1), 512, 0, stream>>>(
                qkvb, qkvb + C, Sb, nullptr, 0.03125f, C,
                N3, N3, T, 0, 0, 0, T / 256, 1, 0, 0, 0, nullptr, 0);

            softmax_causal_kernel<<<dim3(T, 1), 256, 0, stream>>>(Sb, T);

            gemm128_kernel<<<dim3((T / 128) * (C / 256), 1, 1), 512, 0, stream>>>(
                Sb, vTb, xbO, 1.0f, T,
                T, T, C, 0, 0, 0, T / 128, 0, 1);

            gemm256_kernel<<<dim3((T / 256) * (C / 256), 1, 1), 512, 0, stream>>>(
                xbO, wpT, out_b, b_proj, 1.0f, C,
                C, C, C, 0, 0, 0, T / 256, 0, 0, 1, 1, nullptr, 0);
        }
    }
}

// Round 16
// 330.630 us; speedup vs baseline: 1.0552x; 1.0552x over previous
//
#include <hip/hip_runtime.h>
#include <hip/hip_bf16.h>

typedef __hip_bfloat16 bf16_t;
typedef __attribute__((ext_vector_type(8))) __bf16 bf16x8;
typedef __attribute__((ext_vector_type(4))) float f32x4;
typedef __attribute__((ext_vector_type(8))) unsigned short u16x8;

// ---------------------------------------------------------------- helpers

__device__ __forceinline__ void gld_lds16(const void* g, void* l) {
    // async global->LDS, 16B per lane. LDS dest is wave-uniform base + lane*16.
    __builtin_amdgcn_global_load_lds(
        (const __attribute__((address_space(1))) unsigned int*)g,
        (__attribute__((address_space(3))) unsigned int*)l,
        16, 0, 0);
}

__device__ __forceinline__ unsigned short bf16_bits(float x) {
    bf16_t b = __float2bfloat16(x);
    return *reinterpret_cast<unsigned short*>(&b);
}

// ---------------------------------------------------------------- convert x -> bf16

__global__ __launch_bounds__(256) void cvt_f32_bf16_kernel(
    const float* __restrict__ in, bf16_t* __restrict__ out, long n4) {
    long stride = (long)gridDim.x * blockDim.x;
    for (long i = (long)blockIdx.x * blockDim.x + threadIdx.x; i < n4; i += stride) {
        float4 v = reinterpret_cast<const float4*>(in)[i];
        ushort4 o;
        o.x = bf16_bits(v.x);
        o.y = bf16_bits(v.y);
        o.z = bf16_bits(v.z);
        o.w = bf16_bits(v.w);
        reinterpret_cast<ushort4*>(out)[i] = o;
    }
}

// ---------------------------------------------------------------- transposes

__global__ __launch_bounds__(256) void transpose_f32_bf16_kernel(
    const float* __restrict__ in, bf16_t* __restrict__ out, long ldin, long ldout) {
    __shared__ float tile[32][33];
    int c0 = blockIdx.x * 32, r0 = blockIdx.y * 32;
    int x = threadIdx.x;
#pragma unroll
    for (int yy = 0; yy < 4; ++yy) {
        int y = threadIdx.y + yy * 8;
        tile[y][x] = in[(long)(r0 + y) * ldin + c0 + x];
    }
    __syncthreads();
#pragma unroll
    for (int yy = 0; yy < 4; ++yy) {
        int y = threadIdx.y + yy * 8;
        out[(long)(c0 + y) * ldout + r0 + x] = __float2bfloat16(tile[x][y]);
    }
}

__global__ __launch_bounds__(256) void transpose_bf16_kernel(
    const bf16_t* __restrict__ in, bf16_t* __restrict__ out,
    long ldin, long ldout, long sIn, long sOut) {
    __shared__ bf16_t tile[32][33];
    in  += (long)blockIdx.z * sIn;
    out += (long)blockIdx.z * sOut;
    int c0 = blockIdx.x * 32, r0 = blockIdx.y * 32;
    int x = threadIdx.x;
#pragma unroll
    for (int yy = 0; yy < 4; ++yy) {
        int y = threadIdx.y + yy * 8;
        tile[y][x] = in[(long)(r0 + y) * ldin + c0 + x];
    }
    __syncthreads();
#pragma unroll
    for (int yy = 0; yy < 4; ++yy) {
        int y = threadIdx.y + yy * 8;
        out[(long)(c0 + y) * ldout + r0 + x] = tile[x][y];
    }
}

// ---------------------------------------------------------------- 256x256 8-wave GEMM, 1 barrier / K-tile
// (round-7/10 inner loop - best measured. Schedule variants r5/r6/r8/r11/r12
// all regressed; do not re-derive without new counter evidence.)
// swz_mode=1: panel-resident XCD mapping (qkv FETCH 202MB -> 74MB measured).
// V-fusion: cols >= vsplit -> transposed write to Vt[b][c][t] only.

__global__ __launch_bounds__(512, 2) void gemm256_kernel(
    const bf16_t* __restrict__ A, const bf16_t* __restrict__ Bt,
    void* __restrict__ Cp, const float* __restrict__ bias,
    float scale, int K,
    long lda, long ldb, long ldc,
    long strideA, long strideB, long strideC,
    int mtiles, int causal_skip, int causal_klimit, int c_f32, int swz_mode,
    bf16_t* __restrict__ Vt, int vsplit)
{
    __shared__ __align__(16) bf16_t As[3][256 * 32];
    __shared__ __align__(16) bf16_t Bs[3][256 * 32];

    int nwg = gridDim.x;
    int bid = blockIdx.x;
    int bm_t, bn_t;
    if (swz_mode == 1 && (mtiles & 7) == 0 && (nwg & 7) == 0) {
        int xcd = bid & 7;
        int l   = bid >> 3;
        int mpx = mtiles >> 3;
        bm_t = xcd * mpx + (l % mpx);   // bm fast: A group L2-resident
        bn_t = l / mpx;                 // bn slow: B-panels stream
    } else {
        int swz = (bid & 7) * (nwg >> 3) + (bid >> 3);
        bm_t = swz % mtiles; bn_t = swz / mtiles;
    }
    if (causal_skip && bn_t > bm_t) return;
    long bm0 = (long)bm_t * 256, bn0 = (long)bn_t * 256;

    int b = blockIdx.z;
    const char* Ab = (const char*)(A + (long)b * strideA + bm0 * lda);
    const char* Bb = (const char*)(Bt + (long)b * strideB + bn0 * ldb);
    long ldab = lda * 2, ldbb = ldb * 2;

    int tid = threadIdx.x, wave = tid >> 6, lane = tid & 63;
    int wm = wave >> 2, wn = wave & 3;
    int lr = lane & 15, kc = lane >> 4;

    int Kend = K;
    if (causal_klimit) { long kl = bm0 + 256; Kend = (kl < (long)K) ? (int)kl : K; }
    int NT = Kend >> 5;

    int offw = wave * 1024 + lane * 16;
    int rih  = offw >> 6;
    long colswz = (long)(((lane & 3) ^ ((rih >> 1) & 3)) << 4);
    long rowbA0 = (long)rih * ldab, rowbA1 = (long)(rih + 128) * ldab;
    long rowbB0 = (long)rih * ldbb, rowbB1 = (long)(rih + 128) * ldbb;
    int ldsoff = wave * 1024;

    auto STA = [&](int t, int h, int buf) {
        gld_lds16(Ab + (h ? rowbA1 : rowbA0) + (long)t * 64 + colswz,
                  (char*)As + buf * 16384 + h * 8192 + ldsoff);
    };
    auto STB = [&](int t, int h, int buf) {
        gld_lds16(Bb + (h ? rowbB1 : rowbB0) + (long)t * 64 + colswz,
                  (char*)Bs + buf * 16384 + h * 8192 + ldsoff);
    };

    int aoff[8], boff[4];
#pragma unroll
    for (int m = 0; m < 8; ++m) {
        int row = wm * 128 + m * 16 + lr;
        aoff[m] = (row * 64 + kc * 16) ^ (((row >> 1) & 3) << 4);
    }
#pragma unroll
    for (int n = 0; n < 4; ++n) {
        int row = wn * 64 + n * 16 + lr;
        boff[n] = (row * 64 + kc * 16) ^ (((row >> 1) & 3) << 4);
    }

    f32x4 acc[8][4];
#pragma unroll
    for (int m = 0; m < 8; ++m)
#pragma unroll
        for (int n = 0; n < 4; ++n) acc[m][n] = (f32x4){0.f, 0.f, 0.f, 0.f};

    STA(0, 0, 0); STA(0, 1, 0); STB(0, 0, 0); STB(0, 1, 0);
    STA(1, 0, 1); STA(1, 1, 1); STB(1, 0, 1); STB(1, 1, 1);
    asm volatile("s_waitcnt vmcnt(4)" ::: "memory");
    __builtin_amdgcn_s_barrier();

    int cur = 0;

    for (int t = 0; t < NT; ++t) {
        int b2 = cur + 2; if (b2 >= 3) b2 -= 3;
        int t2 = (t + 2 < NT) ? (t + 2) : NT - 1;
        const char* Ac = (const char*)As + cur * 16384;
        const char* Bc = (const char*)Bs + cur * 16384;

        bf16x8 alo[4], ahi[4], bfr[4];
#pragma unroll
        for (int m = 0; m < 4; ++m) alo[m] = *(const bf16x8*)(Ac + aoff[m]);
#pragma unroll
        for (int n = 0; n < 4; ++n) bfr[n] = *(const bf16x8*)(Bc + boff[n]);
#pragma unroll
        for (int m = 0; m < 4; ++m) ahi[m] = *(const bf16x8*)(Ac + aoff[m + 4]);

        STA(t2, 0, b2); STA(t2, 1, b2);
        STB(t2, 0, b2); STB(t2, 1, b2);
        __builtin_amdgcn_sched_barrier(0);

        __builtin_amdgcn_s_setprio(1);
#pragma unroll
        for (int m = 0; m < 4; ++m)
#pragma unroll
            for (int n = 0; n < 4; ++n)
                acc[m][n] = __builtin_amdgcn_mfma_f32_16x16x32_bf16(alo[m], bfr[n], acc[m][n], 0, 0, 0);
#pragma unroll
        for (int m = 0; m < 4; ++m)
#pragma unroll
            for (int n = 0; n < 4; ++n)
                acc[m + 4][n] = __builtin_amdgcn_mfma_f32_16x16x32_bf16(ahi[m], bfr[n], acc[m + 4][n], 0, 0, 0);
        __builtin_amdgcn_s_setprio(0);

        asm volatile("s_waitcnt vmcnt(4)" ::: "memory");
        __builtin_amdgcn_s_barrier();

        cur += 1; if (cur >= 3) cur -= 3;
    }

    asm volatile("s_waitcnt vmcnt(0)" ::: "memory");

#pragma unroll
    for (int m = 0; m < 8; ++m) {
        long row = bm0 + wm * 128 + m * 16 + kc * 4;
#pragma unroll
        for (int n = 0; n < 4; ++n) {
            long col = bn0 + wn * 64 + n * 16 + lr;
            float bv = bias ? bias[col] : 0.f;
            if (Vt && col >= vsplit) {
                long bb = row >> 11;            // T = 2048
                long tl = row & 2047;
                ushort4 pk;
                pk.x = bf16_bits(acc[m][n][0] * scale + bv);
                pk.y = bf16_bits(acc[m][n][1] * scale + bv);
                pk.z = bf16_bits(acc[m][n][2] * scale + bv);
                pk.w = bf16_bits(acc[m][n][3] * scale + bv);
                *reinterpret_cast<ushort4*>(
                    Vt + bb * 2097152 + (col - vsplit) * 2048 + tl) = pk;
            } else if (c_f32) {
                float* Crow = (float*)Cp + (long)b * strideC;
#pragma unroll
                for (int r = 0; r < 4; ++r)
                    Crow[(row + r) * ldc + col] = acc[m][n][r] * scale + bv;
            } else {
                bf16_t* Crow = (bf16_t*)Cp + (long)b * strideC;
#pragma unroll
                for (int r = 0; r < 4; ++r)
                    Crow[(row + r) * ldc + col] = __float2bfloat16(acc[m][n][r] * scale + bv);
            }
        }
    }
}

// ---------------------------------------------------------------- 128x256 8-wave GEMM (PV, complementary-pair mapping)
// Same verified inner-loop pattern as gemm256; M=128, wave tile 64x64,
// acc[4][4] (64 regs); LDS 72 KiB -> 2 blocks/CU.
// pair_mode=1 (PV): 1-D grid of 512 = 2 halves x (8 pairs x 4 bn x 8 batch).
//   pid<256: bm = 15-p (heavy, K 2048..1152); pid>=256: bm = p (light).
//   If dispatch round-robins CUs, CU c hosts pid=c and pid=c+256 ->
//   K(15-p)+K(p) = 17*128 = 2176 const per CU -> balanced makespan
//   (PV-256 was pinned at T(K=2048) with avg T(1152), 1.78x imbalance).
// causal_klimit: Kend = min(bm0+128, K); safe vs softmax zero-fill
// (klim(t) >= bm0+128 for all rows in tile).

__global__ __launch_bounds__(512, 4) void gemm128_kernel(
    const bf16_t* __restrict__ A, const bf16_t* __restrict__ Bt,
    bf16_t* __restrict__ C,
    float scale, int K,
    long lda, long ldb, long ldc,
    long strideA, long strideB, long strideC,
    int mtiles, int causal_skip, int causal_klimit, int pair_mode)
{
    __shared__ __align__(16) bf16_t As[3][128 * 32];
    __shared__ __align__(16) bf16_t Bs[3][256 * 32];

    int bm_t, bn_t, b;
    if (pair_mode) {
        int pid  = blockIdx.x;          // 512 blocks, z = 1
        int half = pid >> 8;
        int r    = pid & 255;
        int p    = r >> 5;              // 0..7
        bn_t     = (r >> 3) & 3;        // 0..3
        b        = r & 7;               // batch
        bm_t     = half ? p : (15 - p);
    } else {
        int nwg = gridDim.x;
        int bid = blockIdx.x;
        int swz = ((nwg & 7) == 0) ? (bid & 7) * (nwg >> 3) + (bid >> 3) : bid;
        bm_t = swz % mtiles; bn_t = swz / mtiles;
        b = blockIdx.z;
    }
    long bm0 = (long)bm_t * 128, bn0 = (long)bn_t * 256;
    if (causal_skip && bn0 > bm0 + 127) return;

    const char* Ab = (const char*)(A + (long)b * strideA + bm0 * lda);
    const char* Bb = (const char*)(Bt + (long)b * strideB + bn0 * ldb);
    long ldab = lda * 2, ldbb = ldb * 2;

    int tid = threadIdx.x, wave = tid >> 6, lane = tid & 63;
    int wm = wave >> 2, wn = wave & 3;   // wm 0..1, wn 0..3
    int lr = lane & 15, kc = lane >> 4;

    int Kend = K;
    if (causal_klimit) { long kl = bm0 + 128; Kend = (kl < (long)K) ? (int)kl : K; }
    int NT = Kend >> 5;                  // >= 4 for all shapes here

    int offw = wave * 1024 + lane * 16;
    int rih  = offw >> 6;                // row 0..127
    long colswz = (long)(((lane & 3) ^ ((rih >> 1) & 3)) << 4);
    long rowbA = (long)rih * ldab;
    long rowbB0 = (long)rih * ldbb, rowbB1 = (long)(rih + 128) * ldbb;
    int ldsoff = wave * 1024;

    auto STA = [&](int t, int buf) {     // full A tile (128 rows) = 1 call
        gld_lds16(Ab + rowbA + (long)t * 64 + colswz,
                  (char*)As + buf * 8192 + ldsoff);
    };
    auto STB = [&](int t, int h, int buf) {
        gld_lds16(Bb + (h ? rowbB1 : rowbB0) + (long)t * 64 + colswz,
                  (char*)Bs + buf * 16384 + h * 8192 + ldsoff);
    };

    int aoff[4], boff[4];
#pragma unroll
    for (int m = 0; m < 4; ++m) {
        int row = wm * 64 + m * 16 + lr;
        aoff[m] = (row * 64 + kc * 16) ^ (((row >> 1) & 3) << 4);
    }
#pragma unroll
    for (int n = 0; n < 4; ++n) {
        int row = wn * 64 + n * 16 + lr;
        boff[n] = (row * 64 + kc * 16) ^ (((row >> 1) & 3) << 4);
    }

    f32x4 acc[4][4];
#pragma unroll
    for (int m = 0; m < 4; ++m)
#pragma unroll
        for (int n = 0; n < 4; ++n) acc[m][n] = (f32x4){0.f, 0.f, 0.f, 0.f};

    STA(0, 0); STB(0, 0, 0); STB(0, 1, 0);
    STA(1, 1); STB(1, 0, 1); STB(1, 1, 1);
    asm volatile("s_waitcnt vmcnt(3)" ::: "memory");
    __builtin_amdgcn_s_barrier();

    int cur = 0;
    for (int t = 0; t < NT; ++t) {
        int b2 = cur + 2; if (b2 >= 3) b2 -= 3;
        int t2 = (t + 2 < NT) ? (t + 2) : NT - 1;
        const char* Ac = (const char*)As + cur * 8192;
        const char* Bc = (const char*)Bs + cur * 16384;

        bf16x8 af[4], bfr[4];
#pragma unroll
        for (int m = 0; m < 4; ++m) af[m] = *(const bf16x8*)(Ac + aoff[m]);
#pragma unroll
        for (int n = 0; n < 4; ++n) bfr[n] = *(const bf16x8*)(Bc + boff[n]);

        STA(t2, b2); STB(t2, 0, b2); STB(t2, 1, b2);
        __builtin_amdgcn_sched_barrier(0);

        __builtin_amdgcn_s_setprio(1);
#pragma unroll
        for (int m = 0; m < 4; ++m)
#pragma unroll
            for (int n = 0; n < 4; ++n)
                acc[m][n] = __builtin_amdgcn_mfma_f32_16x16x32_bf16(af[m], bfr[n], acc[m][n], 0, 0, 0);
        __builtin_amdgcn_s_setprio(0);

        asm volatile("s_waitcnt vmcnt(3)" ::: "memory");
        __builtin_amdgcn_s_barrier();

        cur += 1; if (cur >= 3) cur -= 3;
    }

    asm volatile("s_waitcnt vmcnt(0)" ::: "memory");

#pragma unroll
    for (int m = 0; m < 4; ++m) {
        long row = bm0 + wm * 64 + m * 16 + kc * 4;
#pragma unroll
        for (int n = 0; n < 4; ++n) {
            long col = bn0 + wn * 64 + n * 16 + lr;
            bf16_t* Crow = C + (long)b * strideC;
#pragma unroll
            for (int r = 0; r < 4; ++r)
                Crow[(row + r) * ldc + col] = __float2bfloat16(acc[m][n][r] * scale);
        }
    }
}

// ---------------------------------------------------------------- causal softmax (in-place, bf16)

__global__ __launch_bounds__(256) void softmax_causal_kernel(bf16_t* S, int T) {
    int t = blockIdx.x;
    bf16_t* row = S + ((long)blockIdx.y * T + t) * (long)T;
    int tid = threadIdx.x;
    int s0 = tid * 8;
    int klim = ((t >> 8) + 1) << 8;

    u16x8 raw = {};
    if (s0 <= t) raw = *reinterpret_cast<const u16x8*>(&row[s0]);
    float v[8];
#pragma unroll
    for (int j = 0; j < 8; ++j) v[j] = __uint_as_float(((unsigned)raw[j]) << 16);

    float m = -1e30f;
#pragma unroll
    for (int j = 0; j < 8; ++j)
        if (s0 + j <= t) m = fmaxf(m, v[j]);

    __shared__ float red[8];
#pragma unroll
    for (int o = 32; o; o >>= 1) m = fmaxf(m, __shfl_xor(m, o, 64));
    if ((tid & 63) == 0) red[tid >> 6] = m;
    __syncthreads();
    m = fmaxf(fmaxf(red[0], red[1]), fmaxf(red[2], red[3]));
    __syncthreads();

    float e[8];
    float sum = 0.f;
#pragma unroll
    for (int j = 0; j < 8; ++j) {
        e[j] = (s0 + j <= t) ? __expf(v[j] - m) : 0.f;
        sum += e[j];
    }
#pragma unroll
    for (int o = 32; o; o >>= 1) sum += __shfl_xor(sum, o, 64);
    if ((tid & 63) == 0) red[tid >> 6] = sum;
    __syncthreads();
    sum = red[0] + red[1] + red[2] + red[3];
    float inv = 1.f / sum;

    if (s0 < klim) {
        u16x8 outp;
#pragma unroll
        for (int j = 0; j < 8; ++j) outp[j] = bf16_bits(e[j] * inv);
        *reinterpret_cast<u16x8*>(&row[s0]) = outp;
    }
}

// ---------------------------------------------------------------- launch

extern "C" void kernel_launch(void* const* d_in, const int* in_sizes, int n_in,
                              void* d_out, int out_size, void* d_ws, size_t ws_size,
                              hipStream_t stream) {
    const int B = 8, T = 2048, C = 1024;
    const int M = B * T;            // 16384
    const int N3 = 3 * C;           // 3072

    const float* x      = (const float*)d_in[0];
    const float* w_attn = (const float*)d_in[1];
    const float* b_attn = (const float*)d_in[2];
    const float* w_proj = (const float*)d_in[3];
    const float* b_proj = (const float*)d_in[4];
    float* out = (float*)d_out;     // reference output dtype is fp32

    char* ws = (char*)d_ws;

    // ---- adaptive workspace tiering ----
    const size_t BASE_FULL = 176160768ull;   // weights + qkv + xbO + vT
    const size_t PER_B     = 8388608ull;     // S per batch
    long NB = 0;
    if (ws_size >= BASE_FULL + PER_B) {
        NB = (long)((ws_size - BASE_FULL) / PER_B);
        if (NB > 8) NB = 8;
    }

    if (NB >= 8) {
        // ---------------- full-batch path (pair-mapped PV needs all 8 in S)
        bf16_t* waT = (bf16_t*)(ws);                    // [3C, C]   6.3 MB
        bf16_t* wpT = (bf16_t*)(ws + 6291456);          // [C, C]    2.1 MB
        bf16_t* qkv = (bf16_t*)(ws + 8388608);          // [M, 3C] 100.7 MB (V cols unwritten)
        bf16_t* xbO = (bf16_t*)(ws + 109051904);        // [M, C]   33.5 MB (xb, then O)
        bf16_t* vT  = (bf16_t*)(ws + 142606336);        // [B, C, T] 33.5 MB (fused transposed V)
        bf16_t* S   = (bf16_t*)(ws + 176160768);        // [B, T, T] 67.1 MB

        cvt_f32_bf16_kernel<<<2048, 256, 0, stream>>>(x, xbO, (long)M * C / 4);

        transpose_f32_bf16_kernel<<<dim3(N3 / 32, C / 32, 1), dim3(32, 8), 0, stream>>>(
            w_attn, waT, N3, C);
        transpose_f32_bf16_kernel<<<dim3(C / 32, C / 32, 1), dim3(32, 8), 0, stream>>>(
            w_proj, wpT, C, C);

        // qkv = xb @ w_attn + b_attn  (panel swizzle; V cols -> vT transposed)
        gemm256_kernel<<<dim3((M / 256) * (N3 / 256), 1, 1), 512, 0, stream>>>(
            xbO, waT, qkv, b_attn, 1.0f, C,
            C, C, N3, 0, 0, 0, M / 256, 0, 0, 0, 1, vT, 2 * C);

        // S = (Q K^T)/sqrt(C), causal block-skip (256-tile, r13 best)
        gemm256_kernel<<<dim3((T / 256) * (T / 256), 1, B), 512, 0, stream>>>(
            qkv, qkv + C, S, nullptr, 0.03125f, C,
            N3, N3, T, (long)T * N3, (long)T * N3, (long)T * T, T / 256, 1, 0, 0, 0,
            nullptr, 0);

        softmax_causal_kernel<<<dim3(T, B), 256, 0, stream>>>(S, T);

        // O = P @ V: complementary-pair mapped 128-tiles (balanced makespan)
        gemm128_kernel<<<dim3(512, 1, 1), 512, 0, stream>>>(
            S, vT, xbO, 1.0f, T,
            T, T, C, (long)T * T, (long)C * T, (long)T * C, T / 128, 0, 1, 1);

        // out = O @ w_proj + b_proj   (fp32 store, panel swizzle)
        gemm256_kernel<<<dim3((M / 256) * (C / 256), 1, 1), 512, 0, stream>>>(
            xbO, wpT, out, b_proj, 1.0f, C,
            C, C, C, 0, 0, 0, M / 256, 0, 0, 1, 1, nullptr, 0);
    } else if (NB >= 1) {
        // ---------------- chunked path (pair_mode off)
        bf16_t* waT = (bf16_t*)(ws);
        bf16_t* wpT = (bf16_t*)(ws + 6291456);
        bf16_t* qkv = (bf16_t*)(ws + 8388608);
        bf16_t* xbO = (bf16_t*)(ws + 109051904);
        bf16_t* vT  = (bf16_t*)(ws + 142606336);
        bf16_t* S   = (bf16_t*)(ws + 176160768);

        cvt_f32_bf16_kernel<<<2048, 256, 0, stream>>>(x, xbO, (long)M * C / 4);

        transpose_f32_bf16_kernel<<<dim3(N3 / 32, C / 32, 1), dim3(32, 8), 0, stream>>>(
            w_attn, waT, N3, C);
        transpose_f32_bf16_kernel<<<dim3(C / 32, C / 32, 1), dim3(32, 8), 0, stream>>>(
            w_proj, wpT, C, C);

        gemm256_kernel<<<dim3((M / 256) * (N3 / 256), 1, 1), 512, 0, stream>>>(
            xbO, waT, qkv, b_attn, 1.0f, C,
            C, C, N3, 0, 0, 0, M / 256, 0, 0, 0, 1, vT, 2 * C);

        for (long b0 = 0; b0 < B; b0 += NB) {
            long nb = (B - b0 < NB) ? (B - b0) : NB;
            const bf16_t* qkv_c = qkv + b0 * (long)T * N3;
            bf16_t* O_c = xbO + b0 * (long)T * C;

            gemm256_kernel<<<dim3((T / 256) * (T / 256), 1, nb), 512, 0, stream>>>(
                qkv_c, qkv_c + C, S, nullptr, 0.03125f, C,
                N3, N3, T, (long)T * N3, (long)T * N3, (long)T * T, T / 256, 1, 0, 0, 0,
                nullptr, 0);

            softmax_causal_kernel<<<dim3(T, nb), 256, 0, stream>>>(S, T);

            gemm128_kernel<<<dim3((T / 128) * (C / 256), 1, nb), 512, 0, stream>>>(
                S, vT + b0 * (long)C * T, O_c, 1.0f, T,
                T, T, C, (long)T * T, (long)C * T, (long)T * C, T / 128, 0, 1, 0);
        }

        gemm256_kernel<<<dim3((M / 256) * (C / 256), 1, 1), 512, 0, stream>>>(
            xbO, wpT, out, b_proj, 1.0f, C,
            C, C, C, 0, 0, 0, M / 256, 0, 0, 1, 1, nullptr, 0);
    } else {
        // ---------------- per-batch fallback (36 MB total, unfused V)
        bf16_t* waT  = (bf16_t*)(ws);
        bf16_t* wpT  = (bf16_t*)(ws + 6291456);
        bf16_t* xbO  = (bf16_t*)(ws + 8388608);
        bf16_t* qkvb = (bf16_t*)(ws + 12582912);
        bf16_t* vTb  = (bf16_t*)(ws + 25165824);
        bf16_t* Sb   = (bf16_t*)(ws + 29360128);

        transpose_f32_bf16_kernel<<<dim3(N3 / 32, C / 32, 1), dim3(32, 8), 0, stream>>>(
            w_attn, waT, N3, C);
        transpose_f32_bf16_kernel<<<dim3(C / 32, C / 32, 1), dim3(32, 8), 0, stream>>>(
            w_proj, wpT, C, C);

        for (int b = 0; b < B; ++b) {
            const float* x_b = x + (long)b * T * C;
            float* out_b = out + (long)b * T * C;

            cvt_f32_bf16_kernel<<<1024, 256, 0, stream>>>(x_b, xbO, (long)T * C / 4);

            gemm256_kernel<<<dim3((T / 256) * (N3 / 256), 1, 1), 512, 0, stream>>>(
                xbO, waT, qkvb, b_attn, 1.0f, C,
                C, C, N3, 0, 0, 0, T / 256, 0, 0, 0, 1, nullptr, 0);

            transpose_bf16_kernel<<<dim3(C / 32, T / 32, 1), dim3(32, 8), 0, stream>>>(
                qkvb + 2 * C, vTb, N3, T, 0, 0);

            gemm256_kernel<<<dim3((T / 256) * (T / 256), 1, 1), 512, 0, stream>>>(
                qkvb, qkvb + C, Sb, nullptr, 0.03125f, C,
                N3, N3, T, 0, 0, 0, T / 256, 1, 0, 0, 0, nullptr, 0);

            softmax_causal_kernel<<<dim3(T, 1), 256, 0, stream>>>(Sb, T);

            gemm128_kernel<<<dim3((T / 128) * (C / 256), 1, 1), 512, 0, stream>>>(
                Sb, vTb, xbO, 1.0f, T,
                T, T, C, 0, 0, 0, T / 128, 0, 1, 0);

            gemm256_kernel<<<dim3((T / 256) * (C / 256), 1, 1), 512, 0, stream>>>(
                xbO, wpT, out_b, b_proj, 1.0f, C,
                C, C, C, 0, 0, 0, T / 256, 0, 0, 1, 1, nullptr, 0);
        }
    }
}